// Round 15
// baseline (202.012 us; speedup 1.0000x reference)
//
#include <hip/hip_runtime.h>

#define NN 8000
#define FD 256
#define NEG_SLOPE 0.2f
#define BM 32                 // i rows per block
#define KT 64                 // j per step
#define NSJ 125               // 8000 / 64
#define WROWB 144             // Wt row stride in bytes (64*2 + 16 pad)

typedef __bf16 bf16;
typedef __bf16 bf16x8 __attribute__((ext_vector_type(8)));
typedef float f32x4 __attribute__((ext_vector_type(4)));

#define MFMA __builtin_amdgcn_mfma_f32_16x16x32_bf16

// ---------------- K1: H = X @ W^T + b -> Ht (bf16, [f][i]) ----------------
__global__ __launch_bounds__(256) void k_linear(const float* __restrict__ X,
                                                const float* __restrict__ W,
                                                const float* __restrict__ b,
                                                bf16* __restrict__ Ht) {
    __shared__ float Xs[16][260];
    const int t = threadIdx.x;
    const int i0 = blockIdx.x * 16;
    #pragma unroll
    for (int r = 0; r < 16; ++r)
        Xs[r][t] = X[(size_t)(i0 + r) * FD + t];
    __syncthreads();
    const int f = t;
    float acc[16];
    const float bf_ = b[f];
    #pragma unroll
    for (int ii = 0; ii < 16; ++ii) acc[ii] = bf_;
    for (int k4 = 0; k4 < FD / 4; ++k4) {
        const float4 w4 = *(const float4*)&W[(size_t)f * FD + k4 * 4];
        #pragma unroll
        for (int ii = 0; ii < 16; ++ii) {
            const float4 x4 = *(const float4*)&Xs[ii][k4 * 4];
            acc[ii] += x4.x * w4.x + x4.y * w4.y + x4.z * w4.z + x4.w * w4.w;
        }
    }
    bf16x8 v0, v1;
    #pragma unroll
    for (int ii = 0; ii < 8; ++ii) { v0[ii] = (bf16)acc[ii]; v1[ii] = (bf16)acc[ii + 8]; }
    *(bf16x8*)&Ht[(size_t)f * NN + i0]     = v0;
    *(bf16x8*)&Ht[(size_t)f * NN + i0 + 8] = v1;
}

// ---------------- K2: hs = H@a_src + a_b, hd = H@a_dst ----------------
__global__ __launch_bounds__(256) void k_attn_vec(const bf16* __restrict__ Ht,
                                                  const float* __restrict__ a_src,
                                                  const float* __restrict__ a_dst,
                                                  const float* __restrict__ a_b,
                                                  float* __restrict__ hs,
                                                  float* __restrict__ hd) {
    __shared__ float psh[4][64], pdh[4][64];
    const int t = threadIdx.x;
    const int li = t & 63;
    const int q = t >> 6;
    const int i = blockIdx.x * 64 + li;
    float ps = 0.f, pd = 0.f;
    #pragma unroll 8
    for (int fi = 0; fi < 64; ++fi) {
        const int f = q * 64 + fi;
        const float h = (float)Ht[(size_t)f * NN + i];
        ps += h * a_src[f];
        pd += h * a_dst[f];
    }
    psh[q][li] = ps; pdh[q][li] = pd;
    __syncthreads();
    if (q == 0) {
        ps = psh[0][li] + psh[1][li] + psh[2][li] + psh[3][li];
        pd = pdh[0][li] + pdh[1][li] + pdh[2][li] + pdh[3][li];
        hs[i] = ps + a_b[0];
        hd[i] = pd;
    }
}

// ---------------- K3: wave-specialized fused GAT ----------------
// 768 thr = 12 waves: waves 8-11 = producers (adj->weights->Wt ring[4], one
// slot each, flag release), waves 0-7 = consumers (poll flag, A from LDS,
// B from L2-resident Ht via 1-step register pipeline, 8 MFMA, done++).
// No barriers in the loop; adj stream pace is decoupled from MFMA pace.
// Block owns rows i0..i0+31 end-to-end: direct stores, no atomics, no k_norm.
__global__ __launch_bounds__(768, 3) void k_gat(const bf16* __restrict__ Ht,
                                                const int* __restrict__ adj,
                                                const float* __restrict__ hs,
                                                const float* __restrict__ hd,
                                                float* __restrict__ out) {
    __shared__ __attribute__((aligned(16))) char WtR[4][BM * WROWB];  // 4 x 4.5 KB
    __shared__ int   flagv[4];
    __shared__ int   donev[4];
    __shared__ float lgpart[4][BM];

    const int t  = threadIdx.x;
    const int l  = t & 63;
    const int wv = t >> 6;           // 0..11
    const int i0 = blockIdx.x * BM;
    const int al = l & 15, asl = l >> 4;

    if (t < 4) { flagv[t] = 0; donev[t] = 0; }
    __syncthreads();

    f32x4 acc00 = {0.f,0.f,0.f,0.f}, acc01 = acc00, acc10 = acc00, acc11 = acc00;

    if (wv >= 8) {
        // ================= producer =================
        const int pw = wv - 8;       // owns slot pw; steps s ≡ pw (mod 4)
        const int r  = l & 31;
        const int jh = (l >> 5) * 32;
        const float hsv = hs[i0 + r];
        const int*   adjp = adj + (size_t)(i0 + r) * NN + jh;
        const float* hdp  = hd + jh;
        char* const wrow = WtR[pw] + r * WROWB + jh * 2;
        volatile int* vflag = &flagv[pw];
        volatile int* vdone = &donev[pw];
        float lsum = 0.f;

        #pragma unroll 1
        for (int s = pw; s < NSJ; s += 4) {
            if (s >= 4) {
                while (*vdone != 8) __builtin_amdgcn_s_sleep(2);
                *vdone = 0;
            }
            __builtin_amdgcn_sched_barrier(0);
            const int jb = s * KT;
            int4 a4[8]; float4 h4[8];
            #pragma unroll
            for (int c = 0; c < 8; ++c) {
                a4[c] = *(const int4*)(adjp + jb + c * 4);
                h4[c] = *(const float4*)(hdp + jb + c * 4);
            }
            #pragma unroll
            for (int c2 = 0; c2 < 4; ++c2) {
                bf16x8 w8;
                #pragma unroll
                for (int h = 0; h < 2; ++h) {
                    const int c = c2 * 2 + h;
                    float e0 = hsv + h4[c].x; e0 = fmaxf(e0, NEG_SLOPE * e0);
                    float e1 = hsv + h4[c].y; e1 = fmaxf(e1, NEG_SLOPE * e1);
                    float e2 = hsv + h4[c].z; e2 = fmaxf(e2, NEG_SLOPE * e2);
                    float e3 = hsv + h4[c].w; e3 = fmaxf(e3, NEG_SLOPE * e3);
                    const float w0 = a4[c].x ? __expf(e0) : 0.f;
                    const float w1 = a4[c].y ? __expf(e1) : 0.f;
                    const float w2 = a4[c].z ? __expf(e2) : 0.f;
                    const float w3 = a4[c].w ? __expf(e3) : 0.f;
                    lsum += (w0 + w1) + (w2 + w3);
                    w8[h * 4 + 0] = (bf16)w0; w8[h * 4 + 1] = (bf16)w1;
                    w8[h * 4 + 2] = (bf16)w2; w8[h * 4 + 3] = (bf16)w3;
                }
                *(bf16x8*)(wrow + c2 * 16) = w8;
            }
            asm volatile("s_waitcnt lgkmcnt(0)" ::: "memory");   // Wt visible
            __builtin_amdgcn_sched_barrier(0);
            if (l == 0) *vflag = s + 1;                          // release
        }
        lsum += __shfl_xor(lsum, 32);                            // combine j-halves
        if (l < 32) lgpart[pw][l] = lsum;
    } else {
        // ================= consumer =================
        const int cw = wv;           // f cols cw*32 .. +31
        const bf16* bp00 = Ht + (size_t)(cw * 32 + al) * NN + asl * 8;  // cf0,kg0
        const bf16* bp01 = bp00 + 32;                                    // cf0,kg1
        const bf16* bp10 = bp00 + (size_t)16 * NN;                       // cf1,kg0
        const bf16* bp11 = bp10 + 32;                                    // cf1,kg1

        bf16x8 b00 = *(const bf16x8*)bp00;
        bf16x8 b01 = *(const bf16x8*)bp01;
        bf16x8 b10 = *(const bf16x8*)bp10;
        bf16x8 b11 = *(const bf16x8*)bp11;

        #pragma unroll 1
        for (int s = 0; s < NSJ; ++s) {
            const int slot = s & 3;
            volatile int* vflag = &flagv[slot];
            while (*vflag < s + 1) __builtin_amdgcn_s_sleep(1);
            __builtin_amdgcn_sched_barrier(0);
            asm volatile("" ::: "memory");

            bf16x8 n00, n01, n10, n11;                 // B(s+1), L2
            if (s + 1 < NSJ) {
                const size_t o = (size_t)(s + 1) * KT;
                n00 = *(const bf16x8*)(bp00 + o);
                n01 = *(const bf16x8*)(bp01 + o);
                n10 = *(const bf16x8*)(bp10 + o);
                n11 = *(const bf16x8*)(bp11 + o);
            }
            __builtin_amdgcn_sched_barrier(0);

            const char* Wb = WtR[slot];
            const bf16x8 a00 = *(const bf16x8*)(Wb + (al)      * WROWB + (asl)     * 16);
            const bf16x8 a01 = *(const bf16x8*)(Wb + (al)      * WROWB + (4 + asl) * 16);
            const bf16x8 a10 = *(const bf16x8*)(Wb + (16 + al) * WROWB + (asl)     * 16);
            const bf16x8 a11 = *(const bf16x8*)(Wb + (16 + al) * WROWB + (4 + asl) * 16);
            acc00 = MFMA(a00, b00, acc00, 0, 0, 0); acc00 = MFMA(a01, b01, acc00, 0, 0, 0);
            acc01 = MFMA(a00, b10, acc01, 0, 0, 0); acc01 = MFMA(a01, b11, acc01, 0, 0, 0);
            acc10 = MFMA(a10, b00, acc10, 0, 0, 0); acc10 = MFMA(a11, b01, acc10, 0, 0, 0);
            acc11 = MFMA(a10, b10, acc11, 0, 0, 0); acc11 = MFMA(a11, b11, acc11, 0, 0, 0);

            asm volatile("s_waitcnt lgkmcnt(0)" ::: "memory");   // A reads landed
            if (l == 0) atomicAdd(&donev[slot], 1);

            b00 = n00; b01 = n01; b10 = n10; b11 = n11;
        }
    }

    __syncthreads();   // all 12 waves; lgpart complete

    if (wv < 8) {
        const int cw = wv;
        #pragma unroll
        for (int rb = 0; rb < 2; ++rb) {
            #pragma unroll
            for (int g = 0; g < 4; ++g) {
                const int row = rb * 16 + asl * 4 + g;
                const float lsumr = lgpart[0][row] + lgpart[1][row]
                                  + lgpart[2][row] + lgpart[3][row];
                const float linv = 1.0f / lsumr;
                float* orow = out + (size_t)(i0 + row) * FD + cw * 32 + al;
                if (rb == 0) {
                    orow[0]  = acc00[g] * linv;
                    orow[16] = acc01[g] * linv;
                } else {
                    orow[0]  = acc10[g] * linv;
                    orow[16] = acc11[g] * linv;
                }
            }
        }
    }
}

extern "C" void kernel_launch(void* const* d_in, const int* in_sizes, int n_in,
                              void* d_out, int out_size, void* d_ws, size_t ws_size,
                              hipStream_t stream) {
    const float* X     = (const float*)d_in[0];
    const int*   adj   = (const int*)d_in[1];
    const float* Ww    = (const float*)d_in[2];
    const float* Wb    = (const float*)d_in[3];
    const float* a_src = (const float*)d_in[4];
    const float* a_dst = (const float*)d_in[5];
    const float* a_b   = (const float*)d_in[6];
    float* out = (float*)d_out;

    bf16*  Ht = (bf16*)d_ws;                                  // 4.096 MB
    float* hs = (float*)((char*)d_ws + (size_t)FD * NN * sizeof(bf16));
    float* hd = hs + NN;

    k_linear<<<NN / 16, 256, 0, stream>>>(X, Ww, Wb, Ht);
    k_attn_vec<<<NN / 64, 256, 0, stream>>>(Ht, a_src, a_dst, a_b, hs, hd);
    k_gat<<<NN / BM, 768, 0, stream>>>(Ht, adj, hs, hd, out);
}

// Round 16
// 151.788 us; speedup vs baseline: 1.3309x; 1.3309x over previous
//
#include <hip/hip_runtime.h>

#define NN 8000
#define FD 256
#define NEG_SLOPE 0.2f
#define BM 64                 // i rows per block
#define KT 32                 // j per step
#define JCH 2048              // j chunk (last: 1856)

typedef __bf16 bf16;
typedef __bf16 bf16x8 __attribute__((ext_vector_type(8)));
typedef __bf16 bf16x4 __attribute__((ext_vector_type(4)));
typedef float f32x4 __attribute__((ext_vector_type(4)));

// ---------------- K1: H = X @ W^T + b -> Ht (bf16, [f][i]); zero out/lg ----
__global__ __launch_bounds__(256) void k_linear(const float* __restrict__ X,
                                                const float* __restrict__ W,
                                                const float* __restrict__ b,
                                                bf16* __restrict__ Ht,
                                                float* __restrict__ out,
                                                float* __restrict__ lg) {
    __shared__ float Xs[16][260];
    const int t = threadIdx.x;
    const int i0 = blockIdx.x * 16;
    {   // zero out (8 MB) + lg
        const int gt = blockIdx.x * 256 + t;
        const float4 z4 = {0.f, 0.f, 0.f, 0.f};
        float4* o4 = (float4*)out;
        #pragma unroll
        for (int k = 0; k < 4; ++k) o4[gt + k * 128000] = z4;
        if (gt < NN) lg[gt] = 0.f;
    }
    #pragma unroll
    for (int r = 0; r < 16; ++r)
        Xs[r][t] = X[(size_t)(i0 + r) * FD + t];
    __syncthreads();
    const int f = t;
    float acc[16];
    const float bf_ = b[f];
    #pragma unroll
    for (int ii = 0; ii < 16; ++ii) acc[ii] = bf_;
    for (int k4 = 0; k4 < FD / 4; ++k4) {
        const float4 w4 = *(const float4*)&W[(size_t)f * FD + k4 * 4];
        #pragma unroll
        for (int ii = 0; ii < 16; ++ii) {
            const float4 x4 = *(const float4*)&Xs[ii][k4 * 4];
            acc[ii] += x4.x * w4.x + x4.y * w4.y + x4.z * w4.z + x4.w * w4.w;
        }
    }
    bf16x8 v0, v1;
    #pragma unroll
    for (int ii = 0; ii < 8; ++ii) { v0[ii] = (bf16)acc[ii]; v1[ii] = (bf16)acc[ii + 8]; }
    *(bf16x8*)&Ht[(size_t)f * NN + i0]     = v0;
    *(bf16x8*)&Ht[(size_t)f * NN + i0 + 8] = v1;
}

// ---------------- K2: hs = H@a_src + a_b, hd = H@a_dst ----------------
__global__ __launch_bounds__(256) void k_attn_vec(const bf16* __restrict__ Ht,
                                                  const float* __restrict__ a_src,
                                                  const float* __restrict__ a_dst,
                                                  const float* __restrict__ a_b,
                                                  float* __restrict__ hs,
                                                  float* __restrict__ hd) {
    __shared__ float psh[4][64], pdh[4][64];
    const int t = threadIdx.x;
    const int li = t & 63;
    const int q = t >> 6;
    const int i = blockIdx.x * 64 + li;
    float ps = 0.f, pd = 0.f;
    #pragma unroll 8
    for (int fi = 0; fi < 64; ++fi) {
        const int f = q * 64 + fi;
        const float h = (float)Ht[(size_t)f * NN + i];
        ps += h * a_src[f];
        pd += h * a_dst[f];
    }
    psh[q][li] = ps; pdh[q][li] = pd;
    __syncthreads();
    if (q == 0) {
        ps = psh[0][li] + psh[1][li] + psh[2][li] + psh[3][li];
        pd = pdh[0][li] + pdh[1][li] + pdh[2][li] + pdh[3][li];
        hs[i] = ps + a_b[0];
        hd[i] = pd;
    }
}

// ---------------- K3: all-DMA fused GAT, exact FIFO vmcnt accounting ----------------
// Identical to R14 except: hd staged BEFORE any DMA (vmcnt(0) fence); prologue
// DMA order ad(0), bt(0), ad(1) establishing the queue invariant
// [ad(s), bt(s)a, bt(s)b, ad(s+1)]; steady-state drain vmcnt(4) (NOT 3) so
// ad(s+1) keeps flying -> true 2-step adj lead, step pace decoupled from HBM
// latency. Tails: vmcnt(3) when s+2==NS, vmcnt(0) when s+1==NS.
__global__ __launch_bounds__(512, 2) void k_gat(const bf16* __restrict__ Ht,
                                                const int* __restrict__ adj,
                                                const float* __restrict__ hs,
                                                const float* __restrict__ hd,
                                                float* __restrict__ out,
                                                float* __restrict__ lg) {
    __shared__ __attribute__((aligned(16))) bf16 Bt[2][FD * KT];   // 2 x 16 KB
    __shared__ __attribute__((aligned(16))) int  Adt[3][BM * KT];  // 3 x 8 KB
    __shared__ __attribute__((aligned(16))) bf16 Wt[2][BM * 40];   // 2 x 5 KB (80B rows)
    __shared__ float hd_s[JCH];                                    // 8 KB

    const int t  = threadIdx.x;
    const int l  = t & 63;
    const int wv = t >> 6;
    const int jb = blockIdx.x & 3;
    const int ib = blockIdx.x >> 2;
    const int i0 = ib * BM;
    const int j0 = jb * JCH;
    const int NS = (jb < 3) ? 64 : 58;       // 3*2048 + 1856 = 8000

    // weight mapping: row r (0..63), jslot (0..7) -> 4 j's
    const int r  = t >> 3;
    const int js = t & 7;
    const float hsv = hs[i0 + r];

    // MFMA mapping: wave = (is, fg)
    const int is = wv >> 2, fg = wv & 3;
    const int al = l & 15, asl = l >> 4;
    const int bswz = (asl ^ ((al >> 2) & 3)) << 4;   // Bt read slot byte offset

    auto stage_bt = [&](int s_, int buf) {
        #pragma unroll
        for (int q = 0; q < 2; ++q) {
            const int idx = q * 512 + t;
            const int col = idx >> 2, ks = idx & 3;
            const bf16* src = Ht + (size_t)col * NN + j0 + s_ * KT
                              + ((ks ^ ((col >> 2) & 3)) * 8);
            bf16* dst = &Bt[buf][idx * 8];
            __builtin_amdgcn_global_load_lds(
                (const __attribute__((address_space(1))) void*)src,
                (__attribute__((address_space(3))) void*)dst, 16, 0, 0);
        }
    };
    auto stage_ad = [&](int s_, int buf) {
        const int* src = adj + (size_t)(i0 + r) * NN + j0 + s_ * KT + js * 4;
        int* dst = &Adt[buf][t * 4];    // linear: row r*32 + js*4 == t*4
        __builtin_amdgcn_global_load_lds(
            (const __attribute__((address_space(1))) void*)src,
            (__attribute__((address_space(3))) void*)dst, 16, 0, 0);
    };

    // ---- prologue: hd FIRST (and fully drained), then DMA ad(0), bt(0), ad(1)
    {
        const int jg = j0 + t * 4;
        float4 h4 = {0.f, 0.f, 0.f, 0.f};
        if (jg + 3 < NN) h4 = *(const float4*)(hd + jg);
        *(float4*)&hd_s[t * 4] = h4;
    }
    asm volatile("s_waitcnt vmcnt(0) lgkmcnt(0)" ::: "memory");  // hd out of the FIFO
    stage_ad(0, 0);
    stage_bt(0, 0);
    stage_ad(1, 1);
    __builtin_amdgcn_s_barrier();     // hd_s visible to all waves

    f32x4 acc[2][4];
    #pragma unroll
    for (int rb = 0; rb < 2; ++rb)
        #pragma unroll
        for (int cf = 0; cf < 4; ++cf) acc[rb][cf] = (f32x4){0.f, 0.f, 0.f, 0.f};
    float lsum = 0.f;

    #pragma unroll 1
    for (int s = 0; s < NS; ++s) {
        const int bt = s & 1;
        // 1) issue next DMAs: bt(s+1) first, then ad(s+2) (FIFO order matters)
        if (s + 1 < NS) stage_bt(s + 1, (s + 1) & 1);
        if (s + 2 < NS) stage_ad(s + 2, (s + 2) % 3);
        // 2) exact drain: complete ad(s)+bt(s); leave ad(s+1), bt(s+1), ad(s+2)
        if (s + 2 < NS)      asm volatile("s_waitcnt vmcnt(4)" ::: "memory");
        else if (s + 1 < NS) asm volatile("s_waitcnt vmcnt(3)" ::: "memory");
        else                 asm volatile("s_waitcnt vmcnt(0)" ::: "memory");

        // 3) weight phase: own 16B of Adt + hd_s broadcast; 4 exps -> Wt
        {
            const int4 a4 = *(const int4*)&Adt[s % 3][t * 4];
            const float4 h4 = *(const float4*)&hd_s[s * KT + js * 4];
            float e, w0, w1, w2, w3;
            e = hsv + h4.x; e = fmaxf(e, NEG_SLOPE * e); w0 = a4.x ? __expf(e) : 0.f;
            e = hsv + h4.y; e = fmaxf(e, NEG_SLOPE * e); w1 = a4.y ? __expf(e) : 0.f;
            e = hsv + h4.z; e = fmaxf(e, NEG_SLOPE * e); w2 = a4.z ? __expf(e) : 0.f;
            e = hsv + h4.w; e = fmaxf(e, NEG_SLOPE * e); w3 = a4.w ? __expf(e) : 0.f;
            lsum += (w0 + w1) + (w2 + w3);
            bf16x4 w4v;
            w4v[0] = (bf16)w0; w4v[1] = (bf16)w1; w4v[2] = (bf16)w2; w4v[3] = (bf16)w3;
            *(bf16x4*)((char*)&Wt[bt][0] + r * 80 + js * 8) = w4v;
        }
        asm volatile("s_waitcnt lgkmcnt(0)" ::: "memory");
        __builtin_amdgcn_s_barrier();

        // 4) MFMA phase: A from Wt (padded rows), B from Bt (slot-XOR)
        {
            const char* Ab = (const char*)&Wt[bt][0];
            const char* Bb = (const char*)&Bt[bt][0];
            bf16x8 a[2], b[4];
            #pragma unroll
            for (int rb = 0; rb < 2; ++rb)
                a[rb] = *(const bf16x8*)(Ab + (is * 32 + rb * 16 + al) * 80 + asl * 16);
            #pragma unroll
            for (int cf = 0; cf < 4; ++cf)
                b[cf] = *(const bf16x8*)(Bb + (fg * 64 + cf * 16 + al) * 64 + bswz);
            #pragma unroll
            for (int rb = 0; rb < 2; ++rb)
                #pragma unroll
                for (int cf = 0; cf < 4; ++cf)
                    acc[rb][cf] = __builtin_amdgcn_mfma_f32_16x16x32_bf16(
                        a[rb], b[cf], acc[rb][cf], 0, 0, 0);
        }
        asm volatile("s_waitcnt lgkmcnt(0)" ::: "memory");
        __builtin_amdgcn_s_barrier();
    }

    // ---- epilogue: row sums (8 threads share row r) + atomic numerator
    lsum += __shfl_xor(lsum, 1);
    lsum += __shfl_xor(lsum, 2);
    lsum += __shfl_xor(lsum, 4);
    if ((t & 7) == 0) atomicAdd(&lg[i0 + r], lsum);

    #pragma unroll
    for (int rb = 0; rb < 2; ++rb)
        #pragma unroll
        for (int cf = 0; cf < 4; ++cf)
            #pragma unroll
            for (int g = 0; g < 4; ++g)
                atomicAdd(&out[(size_t)(i0 + is * 32 + rb * 16 + asl * 4 + g) * FD
                               + fg * 64 + cf * 16 + al], acc[rb][cf][g]);
}

// ---------------- K4: normalize by row sums ----------------
__global__ __launch_bounds__(256) void k_norm(float* __restrict__ out,
                                              const float* __restrict__ lg) {
    const int i = blockIdx.x;
    const float rinv = 1.0f / lg[i];
    out[(size_t)i * FD + threadIdx.x] *= rinv;
}

extern "C" void kernel_launch(void* const* d_in, const int* in_sizes, int n_in,
                              void* d_out, int out_size, void* d_ws, size_t ws_size,
                              hipStream_t stream) {
    const float* X     = (const float*)d_in[0];
    const int*   adj   = (const int*)d_in[1];
    const float* Ww    = (const float*)d_in[2];
    const float* Wb    = (const float*)d_in[3];
    const float* a_src = (const float*)d_in[4];
    const float* a_dst = (const float*)d_in[5];
    const float* a_b   = (const float*)d_in[6];
    float* out = (float*)d_out;

    bf16*  Ht = (bf16*)d_ws;                                  // 4.096 MB
    float* hs = (float*)((char*)d_ws + (size_t)FD * NN * sizeof(bf16));
    float* hd = hs + NN;
    float* lg = hd + NN;

    k_linear<<<NN / 16, 256, 0, stream>>>(X, Ww, Wb, Ht, out, lg);
    k_attn_vec<<<NN / 64, 256, 0, stream>>>(Ht, a_src, a_dst, a_b, hs, hd);
    k_gat<<<125 * 4, 512, 0, stream>>>(Ht, adj, hs, hd, out, lg);
    k_norm<<<NN, 256, 0, stream>>>(out, lg);
}